// Round 9
// baseline (487.932 us; speedup 1.0000x reference)
//
#include <hip/hip_runtime.h>
#include <math.h>

#define C_DIM 512
#define T_DIM 2048
#define B_DIM 8

typedef _Float16 f16;
typedef __attribute__((ext_vector_type(8))) _Float16 half8;
typedef __attribute__((ext_vector_type(4))) _Float16 half4;
typedef __attribute__((ext_vector_type(4))) float floatx4;

// ---------------------------------------------------------------------------
// prep: z<8 -> transpose x[b=z] [C][T] fp32 -> xt [T][C] fp16 (32x32 tiles);
//       z==8 -> convert 4 weight matrices to fp16 (+ concat theta/phi bias).
// ---------------------------------------------------------------------------
__global__ __launch_bounds__(256) void prep_kernel(
    const float* __restrict__ x, f16* __restrict__ xt,
    const float* __restrict__ w0, const float* __restrict__ w1,
    const float* __restrict__ w2, const float* __restrict__ w3,
    f16* __restrict__ o0, f16* __restrict__ o1,
    f16* __restrict__ o2, f16* __restrict__ o3,
    const float* __restrict__ b0, const float* __restrict__ b1,
    float* __restrict__ btp)
{
    const int tid = threadIdx.x;
    if (blockIdx.z == 8) {
        const int idx = blockIdx.y * 64 + blockIdx.x;    // 0..1023
        const int wsel = idx >> 8, blk = idx & 255;
        const float* src; f16* dst;
        switch (wsel) {
            case 0:  src = w0; dst = o0; break;
            case 1:  src = w1; dst = o1; break;
            case 2:  src = w2; dst = o2; break;
            default: src = w3; dst = o3; break;
        }
        const int e = blk * 1024 + tid * 4;
        const float4 v = *(const float4*)(src + e);
        half4 h; h[0] = (f16)v.x; h[1] = (f16)v.y; h[2] = (f16)v.z; h[3] = (f16)v.w;
        *(half4*)(dst + e) = h;
        if (idx == 0) {
            const int i = tid * 4;
            const float4 bv = (i < 512) ? *(const float4*)(b0 + i)
                                        : *(const float4*)(b1 + i - 512);
            *(float4*)(btp + i) = bv;
        }
        return;
    }
    __shared__ float xs[32][33];
    const int b  = blockIdx.z;
    const int t0 = blockIdx.x * 32, c0 = blockIdx.y * 32;
    const float* xb = x + (size_t)b * C_DIM * T_DIM;
    const int r = tid >> 3, q = tid & 7;

    const float4 v = *(const float4*)(xb + (size_t)(c0 + r) * T_DIM + t0 + q * 4);
    xs[r][q * 4 + 0] = v.x; xs[r][q * 4 + 1] = v.y;
    xs[r][q * 4 + 2] = v.z; xs[r][q * 4 + 3] = v.w;
    __syncthreads();

    f16* xtb = xt + (size_t)b * C_DIM * T_DIM;
    half4 h;
    h[0] = (f16)xs[q * 4 + 0][r]; h[1] = (f16)xs[q * 4 + 1][r];
    h[2] = (f16)xs[q * 4 + 2][r]; h[3] = (f16)xs[q * 4 + 3][r];
    *(half4*)(xtb + (size_t)(t0 + r) * C_DIM + c0 + q * 4) = h;
}

// ---------------------------------------------------------------------------
// LDS-FREE TN MFMA GEMM: C[i][j] = sum_k A[i][k] * B[j][k]
// R6-R8 showed the 128x128 LDS structure is LDS-bandwidth bound (48 KB
// LDS traffic per 78-cyc MFMA window -> MfmaUtil ~26% cap). Here each wave
// loads its MFMA fragments DIRECTLY from global: A-operand layout is
// row = l16 (16 rows), k = quad*8..+7 -> the 4 quads cover a full 64 B
// line per row; a wave load = 16 full cache lines = same transaction count
// as a coalesced load. No LDS, no barriers, no bank conflicts. Intra-block
// 2x fragment redundancy is served by L1/L2; the XCD-aware tile remap
// (R7-proven: FETCH 148->49 MB) keeps tiles resident in the owning XCD L2.
// Named-scalar distance-2 register pipeline (sets 0/1 for iters t/t+1,
// reloaded for t+2/t+3 after consumption) -- no arrays with runtime
// indices anywhere (R5/R8 scratch-spill lesson).
// MODE: 0 = f16 store; 1 = f16 relu(+bias[col]); 2 = f16 relu(+bias[row]);
// 3 = fp32 relu(+bias[row]) + resid.
// ---------------------------------------------------------------------------
#define MFMA16(A0, A1, A2, A3, B0, B1, B2, B3)                                 \
    acc[0][0] = __builtin_amdgcn_mfma_f32_16x16x32_f16(A0, B0, acc[0][0], 0, 0, 0); \
    acc[0][1] = __builtin_amdgcn_mfma_f32_16x16x32_f16(A0, B1, acc[0][1], 0, 0, 0); \
    acc[0][2] = __builtin_amdgcn_mfma_f32_16x16x32_f16(A0, B2, acc[0][2], 0, 0, 0); \
    acc[0][3] = __builtin_amdgcn_mfma_f32_16x16x32_f16(A0, B3, acc[0][3], 0, 0, 0); \
    acc[1][0] = __builtin_amdgcn_mfma_f32_16x16x32_f16(A1, B0, acc[1][0], 0, 0, 0); \
    acc[1][1] = __builtin_amdgcn_mfma_f32_16x16x32_f16(A1, B1, acc[1][1], 0, 0, 0); \
    acc[1][2] = __builtin_amdgcn_mfma_f32_16x16x32_f16(A1, B2, acc[1][2], 0, 0, 0); \
    acc[1][3] = __builtin_amdgcn_mfma_f32_16x16x32_f16(A1, B3, acc[1][3], 0, 0, 0); \
    acc[2][0] = __builtin_amdgcn_mfma_f32_16x16x32_f16(A2, B0, acc[2][0], 0, 0, 0); \
    acc[2][1] = __builtin_amdgcn_mfma_f32_16x16x32_f16(A2, B1, acc[2][1], 0, 0, 0); \
    acc[2][2] = __builtin_amdgcn_mfma_f32_16x16x32_f16(A2, B2, acc[2][2], 0, 0, 0); \
    acc[2][3] = __builtin_amdgcn_mfma_f32_16x16x32_f16(A2, B3, acc[2][3], 0, 0, 0); \
    acc[3][0] = __builtin_amdgcn_mfma_f32_16x16x32_f16(A3, B0, acc[3][0], 0, 0, 0); \
    acc[3][1] = __builtin_amdgcn_mfma_f32_16x16x32_f16(A3, B1, acc[3][1], 0, 0, 0); \
    acc[3][2] = __builtin_amdgcn_mfma_f32_16x16x32_f16(A3, B2, acc[3][2], 0, 0, 0); \
    acc[3][3] = __builtin_amdgcn_mfma_f32_16x16x32_f16(A3, B3, acc[3][3], 0, 0, 0);

template<int MODE>
__global__ __launch_bounds__(256) void gemm_direct(
    const f16* __restrict__ A, size_t sA, int lda,
    const f16* __restrict__ B, size_t sB, int ldb,
    void* __restrict__ Cp, size_t sC, int ldc,
    const float* __restrict__ bias,
    const float* __restrict__ resid, size_t sR,
    int K, int RI, int RJ)
{
    // XCD-aware tile mapping: 8 regions of RI x RJ tiles, one per XCD
    const int gx = gridDim.x;
    const int flat = blockIdx.y * gx + blockIdx.x;
    const int region = flat & 7;
    const int idx = flat >> 3;
    const int NRJ = gx / RJ;
    const int rI = region / NRJ, rJ = region % NRJ;
    const int ii = idx / RJ, jj = idx % RJ;
    const int i0 = (rI * RI + ii) * 128;
    const int j0 = (rJ * RJ + jj) * 128;

    const int bz = blockIdx.z;
    A += (size_t)bz * sA;
    B += (size_t)bz * sB;

    const int tid  = threadIdx.x;
    const int lane = tid & 63;
    const int wave = tid >> 6;
    const int wy = wave >> 1, wx = wave & 1;
    const int quad = lane >> 4, l16 = lane & 15;

    // fragment base pointers: wave (wy,wx) owns 64x64 output; lane reads
    // A[row = i0+wy*64+mi*16+l16][k = quad*8 ..+7], same pattern for B.
    const f16* aB = A + (size_t)(i0 + wy * 64 + l16) * lda + quad * 8;
    const f16* bB = B + (size_t)(j0 + wx * 64 + l16) * ldb + quad * 8;
    const f16* aP0 = aB;
    const f16* aP1 = aB + (size_t)16 * lda;
    const f16* aP2 = aB + (size_t)32 * lda;
    const f16* aP3 = aB + (size_t)48 * lda;
    const f16* bP0 = bB;
    const f16* bP1 = bB + (size_t)16 * ldb;
    const f16* bP2 = bB + (size_t)32 * ldb;
    const f16* bP3 = bB + (size_t)48 * ldb;

    const int nt = K >> 5;   // even for all our shapes (16 or 64)

    // prologue: set0 = iter 0, set1 = iter 1
    half8 a0_0 = *(const half8*)(aP0);      half8 a0_1 = *(const half8*)(aP1);
    half8 a0_2 = *(const half8*)(aP2);      half8 a0_3 = *(const half8*)(aP3);
    half8 b0_0 = *(const half8*)(bP0);      half8 b0_1 = *(const half8*)(bP1);
    half8 b0_2 = *(const half8*)(bP2);      half8 b0_3 = *(const half8*)(bP3);
    half8 a1_0 = *(const half8*)(aP0 + 32); half8 a1_1 = *(const half8*)(aP1 + 32);
    half8 a1_2 = *(const half8*)(aP2 + 32); half8 a1_3 = *(const half8*)(aP3 + 32);
    half8 b1_0 = *(const half8*)(bP0 + 32); half8 b1_1 = *(const half8*)(bP1 + 32);
    half8 b1_2 = *(const half8*)(bP2 + 32); half8 b1_3 = *(const half8*)(bP3 + 32);

    floatx4 acc[4][4] = {};

    for (int t = 0; t < nt; t += 2) {
        // even iter: consume set0, then reload set0 for t+2
        MFMA16(a0_0, a0_1, a0_2, a0_3, b0_0, b0_1, b0_2, b0_3)
        if (t + 2 < nt) {
            const int off = (t + 2) * 32;
            a0_0 = *(const half8*)(aP0 + off); a0_1 = *(const half8*)(aP1 + off);
            a0_2 = *(const half8*)(aP2 + off); a0_3 = *(const half8*)(aP3 + off);
            b0_0 = *(const half8*)(bP0 + off); b0_1 = *(const half8*)(bP1 + off);
            b0_2 = *(const half8*)(bP2 + off); b0_3 = *(const half8*)(bP3 + off);
        }
        // odd iter: consume set1, then reload set1 for t+3
        MFMA16(a1_0, a1_1, a1_2, a1_3, b1_0, b1_1, b1_2, b1_3)
        if (t + 3 < nt) {
            const int off = (t + 3) * 32;
            a1_0 = *(const half8*)(aP0 + off); a1_1 = *(const half8*)(aP1 + off);
            a1_2 = *(const half8*)(aP2 + off); a1_3 = *(const half8*)(aP3 + off);
            b1_0 = *(const half8*)(bP0 + off); b1_1 = *(const half8*)(bP1 + off);
            b1_2 = *(const half8*)(bP2 + off); b1_3 = *(const half8*)(bP3 + off);
        }
    }

    // epilogue: C/D layout col = lane&15, row = quad*4 + reg (m89-verified)
    #pragma unroll
    for (int mi = 0; mi < 4; ++mi) {
        #pragma unroll
        for (int ni = 0; ni < 4; ++ni) {
            const int col = j0 + wx * 64 + ni * 16 + l16;
            #pragma unroll
            for (int r = 0; r < 4; ++r) {
                const int row = i0 + wy * 64 + mi * 16 + quad * 4 + r;
                float v = acc[mi][ni][r];
                if (MODE == 1) { v += bias[col]; v = v > 0.f ? v : 0.f; }
                if (MODE == 2) { v += bias[row]; v = v > 0.f ? v : 0.f; }
                if (MODE == 3) {
                    v += bias[row];
                    v = v > 0.f ? v : 0.f;
                    v += resid[(size_t)bz * sR + (size_t)row * ldc + col];
                    ((float*)Cp)[(size_t)bz * sC + (size_t)row * ldc + col] = v;
                } else {
                    ((f16*)Cp)[(size_t)bz * sC + (size_t)row * ldc + col] = (f16)v;
                }
            }
        }
    }
}

// ---------------------------------------------------------------------------
// in-place fp16 softmax over rows of 2048 (fp32 math)
// ---------------------------------------------------------------------------
__global__ __launch_bounds__(256) void softmax_f16_kernel(f16* __restrict__ S)
{
    f16* p = S + (size_t)blockIdx.x * T_DIM;
    const int tid = threadIdx.x;

    half8 hv = *((const half8*)p + tid);
    float v[8];
    float lmax = -1e30f;
    #pragma unroll
    for (int c = 0; c < 8; ++c) { v[c] = (float)hv[c]; lmax = fmaxf(lmax, v[c]); }
    #pragma unroll
    for (int off = 32; off; off >>= 1)
        lmax = fmaxf(lmax, __shfl_down(lmax, off));
    __shared__ float redm[4];
    if ((tid & 63) == 0) redm[tid >> 6] = lmax;
    __syncthreads();
    const float m = fmaxf(fmaxf(redm[0], redm[1]), fmaxf(redm[2], redm[3]));

    float lsum = 0.f;
    #pragma unroll
    for (int c = 0; c < 8; ++c) { v[c] = __expf(v[c] - m); lsum += v[c]; }
    #pragma unroll
    for (int off = 32; off; off >>= 1)
        lsum += __shfl_down(lsum, off);
    __shared__ float reds[4];
    if ((tid & 63) == 0) reds[tid >> 6] = lsum;
    __syncthreads();
    const float inv = 1.f / (reds[0] + reds[1] + reds[2] + reds[3]);

    #pragma unroll
    for (int c = 0; c < 8; ++c) hv[c] = (f16)(v[c] * inv);
    *((half8*)p + tid) = hv;
}

// ---------------------------------------------------------------------------
extern "C" void kernel_launch(void* const* d_in, const int* in_sizes, int n_in,
                              void* d_out, int out_size, void* d_ws, size_t ws_size,
                              hipStream_t stream)
{
    const float* x       = (const float*)d_in[0];
    const float* w_theta = (const float*)d_in[1];
    const float* b_theta = (const float*)d_in[2];
    const float* w_phi   = (const float*)d_in[3];
    const float* b_phi   = (const float*)d_in[4];
    const float* w_g     = (const float*)d_in[5];
    const float* b_g     = (const float*)d_in[6];
    const float* w_w     = (const float*)d_in[7];
    const float* b_w     = (const float*)d_in[8];
    float* out = (float*)d_out;

    const size_t FE = (size_t)B_DIM * C_DIM * T_DIM;   // 8.4M
    const size_t TC = (size_t)T_DIM * C_DIM;
    const size_t TT = (size_t)T_DIM * T_DIM;

    f16* xt      = (f16*)d_ws;
    f16* wtp     = xt + FE;              // merged theta|phi weights [1024][512]
    f16* wg_h    = wtp + 524288;
    f16* ww_h    = wg_h + 262144;
    float* btp   = (float*)(ww_h + 262144);   // merged bias [1024] fp32
    f16* tp      = (f16*)(btp + 1024);   // theta|phi acts [B][T][1024]
    f16* g       = tp + (size_t)B_DIM * T_DIM * 1024;
    f16* scores  = g + FE;               // B*T*T f16 = 67 MB
    f16* feature = tp;                   // tp dead after scores GEMM

    const dim3 blk(256);

    prep_kernel<<<dim3(64, 16, 9), blk, 0, stream>>>(
        x, xt, w_theta, w_phi, w_g, w_w,
        wtp, wtp + 262144, wg_h, ww_h, b_theta, b_phi, btp);

    // merged theta|phi conv: tp[t][0:1024] = relu(xt . wtp + btp)  M=T,N=1024
    gemm_direct<1><<<dim3(8, 16, B_DIM), blk, 0, stream>>>(
        xt, TC, C_DIM, wtp, 0, C_DIM, tp, (size_t)T_DIM * 1024, 1024,
        btp, nullptr, 0, C_DIM, 4, 4);
    // g[c][t] = relu(w_g . xt + b_g[c])   M=C, N=T
    gemm_direct<2><<<dim3(16, 4, B_DIM), blk, 0, stream>>>(
        wg_h, 0, C_DIM, xt, TC, C_DIM, g, TC, T_DIM,
        b_g, nullptr, 0, C_DIM, 2, 4);
    // scores[i][j] = theta . phi   (theta = tp cols 0:512, phi = cols 512:1024)
    gemm_direct<0><<<dim3(16, 16, B_DIM), blk, 0, stream>>>(
        tp, (size_t)T_DIM * 1024, 1024, tp + 512, (size_t)T_DIM * 1024, 1024,
        scores, TT, T_DIM, nullptr, nullptr, 0, C_DIM, 4, 8);
    softmax_f16_kernel<<<dim3(B_DIM * T_DIM), blk, 0, stream>>>(scores);
    // feature[i][c] = attn . g   M=T, N=C, K=T
    gemm_direct<0><<<dim3(4, 16, B_DIM), blk, 0, stream>>>(
        scores, TT, T_DIM, g, TC, T_DIM, feature, TC, C_DIM,
        nullptr, nullptr, 0, T_DIM, 2, 4);
    // out[c][t] = relu(w_w . feature + b_w[c]) + x   M=C, N=T
    gemm_direct<3><<<dim3(16, 4, B_DIM), blk, 0, stream>>>(
        ww_h, 0, C_DIM, feature, TC, C_DIM, out, TC, T_DIM,
        b_w, x, TC, C_DIM, 2, 4);
}

// Round 10
// 476.793 us; speedup vs baseline: 1.0234x; 1.0234x over previous
//
#include <hip/hip_runtime.h>
#include <math.h>

#define C_DIM 512
#define T_DIM 2048
#define B_DIM 8

typedef _Float16 f16;
typedef __attribute__((ext_vector_type(8))) _Float16 half8;
typedef __attribute__((ext_vector_type(4))) _Float16 half4;
typedef __attribute__((ext_vector_type(4))) float floatx4;

// ---------------------------------------------------------------------------
// prep: z<8 -> transpose x[b=z] [C][T] fp32 -> xt [T][C] fp16 (32x32 tiles);
//       z==8 -> convert 4 weight matrices to fp16 (+ concat theta/phi bias).
// ---------------------------------------------------------------------------
__global__ __launch_bounds__(256) void prep_kernel(
    const float* __restrict__ x, f16* __restrict__ xt,
    const float* __restrict__ w0, const float* __restrict__ w1,
    const float* __restrict__ w2, const float* __restrict__ w3,
    f16* __restrict__ o0, f16* __restrict__ o1,
    f16* __restrict__ o2, f16* __restrict__ o3,
    const float* __restrict__ b0, const float* __restrict__ b1,
    float* __restrict__ btp)
{
    const int tid = threadIdx.x;
    if (blockIdx.z == 8) {
        const int idx = blockIdx.y * 64 + blockIdx.x;    // 0..1023
        const int wsel = idx >> 8, blk = idx & 255;
        const float* src; f16* dst;
        switch (wsel) {
            case 0:  src = w0; dst = o0; break;
            case 1:  src = w1; dst = o1; break;
            case 2:  src = w2; dst = o2; break;
            default: src = w3; dst = o3; break;
        }
        const int e = blk * 1024 + tid * 4;
        const float4 v = *(const float4*)(src + e);
        half4 h; h[0] = (f16)v.x; h[1] = (f16)v.y; h[2] = (f16)v.z; h[3] = (f16)v.w;
        *(half4*)(dst + e) = h;
        if (idx == 0) {
            const int i = tid * 4;
            const float4 bv = (i < 512) ? *(const float4*)(b0 + i)
                                        : *(const float4*)(b1 + i - 512);
            *(float4*)(btp + i) = bv;
        }
        return;
    }
    __shared__ float xs[32][33];
    const int b  = blockIdx.z;
    const int t0 = blockIdx.x * 32, c0 = blockIdx.y * 32;
    const float* xb = x + (size_t)b * C_DIM * T_DIM;
    const int r = tid >> 3, q = tid & 7;

    const float4 v = *(const float4*)(xb + (size_t)(c0 + r) * T_DIM + t0 + q * 4);
    xs[r][q * 4 + 0] = v.x; xs[r][q * 4 + 1] = v.y;
    xs[r][q * 4 + 2] = v.z; xs[r][q * 4 + 3] = v.w;
    __syncthreads();

    f16* xtb = xt + (size_t)b * C_DIM * T_DIM;
    half4 h;
    h[0] = (f16)xs[q * 4 + 0][r]; h[1] = (f16)xs[q * 4 + 1][r];
    h[2] = (f16)xs[q * 4 + 2][r]; h[3] = (f16)xs[q * 4 + 3][r];
    *(half4*)(xtb + (size_t)(t0 + r) * C_DIM + c0 + q * 4) = h;
}

// ---------------------------------------------------------------------------
// BIG-TILE TN MFMA GEMM: C[i][j] = sum_k A[i][k] * B[j][k]
// 256x256 block tile, 4 waves, wave tile 128x128 (8x8 grid of 16x16x32).
// Rationale (R6-R9 evidence): the 64x64-wave structure moves 48 KB through
// LDS per 155 MFMA-cyc window -> LDS-BW ceiling ~40% MfmaUtil (measured 26%).
// Wave FLOP per LDS-read-byte = M*N/(M+N): 64x64 -> 32, 128x128 -> 64.
// This kernel halves LDS reads per FLOP, quarters barriers and global
// fetches per FLOP. Cost: acc[8][8] = 256 VGPR -> 1 wave/SIMD, 1 block/CU;
// latency hidden by ILP (64 independent MFMA chains).
// All loop-carried register state is named scalars or fully-unrolled
// compile-time-indexed arrays (R5/R8: runtime indices -> scratch spills).
// Distance-2 named staging sets; LDS dbuf; XOR slot swizzle; XCD-aware
// tile remap (R7: FETCH 148->49 MB).
// MODE: 0 = f16 store; 1 = f16 relu(+bias[col]); 2 = f16 relu(+bias[row]);
// 3 = fp32 relu(+bias[row]) + resid.
// ---------------------------------------------------------------------------
#define COMPUTE(P)                                                            \
    {                                                                         \
        half8 af[8], bf[8];                                                   \
        _Pragma("unroll")                                                     \
        for (int mi = 0; mi < 8; ++mi)                                        \
            af[mi] = *(const half8*)&As[P][(wy * 128 + mi * 16 + l16) * 32 + xa]; \
        _Pragma("unroll")                                                     \
        for (int ni = 0; ni < 8; ++ni)                                        \
            bf[ni] = *(const half8*)&Bs[P][(wx * 128 + ni * 16 + l16) * 32 + xa]; \
        _Pragma("unroll")                                                     \
        for (int mi = 0; mi < 8; ++mi)                                        \
            _Pragma("unroll")                                                 \
            for (int ni = 0; ni < 8; ++ni)                                    \
                acc[mi][ni] = __builtin_amdgcn_mfma_f32_16x16x32_f16(         \
                    af[mi], bf[ni], acc[mi][ni], 0, 0, 0);                    \
    }

template<int MODE>
__global__ __launch_bounds__(256, 1) void gemm_big(
    const f16* __restrict__ A, size_t sA, int lda,
    const f16* __restrict__ B, size_t sB, int ldb,
    void* __restrict__ Cp, size_t sC, int ldc,
    const float* __restrict__ bias,
    const float* __restrict__ resid, size_t sR,
    int K, int RI, int RJ)
{
    __shared__ __align__(16) f16 As[2][256 * 32];   // 2 x 16 KB
    __shared__ __align__(16) f16 Bs[2][256 * 32];

    // XCD-aware tile mapping: 8 regions of RI x RJ tiles, one per XCD
    const int gx = gridDim.x;
    const int flat = blockIdx.y * gx + blockIdx.x;
    const int region = flat & 7;
    const int idx = flat >> 3;
    const int NRJ = gx / RJ;
    const int rI = region / NRJ, rJ = region % NRJ;
    const int ii = idx / RJ, jj = idx % RJ;
    const int i0 = (rI * RI + ii) * 256;
    const int j0 = (rJ * RJ + jj) * 256;

    const int bz = blockIdx.z;
    A += (size_t)bz * sA;
    B += (size_t)bz * sB;

    const int tid  = threadIdx.x;
    const int lane = tid & 63;
    const int wave = tid >> 6;
    const int wy = wave >> 1, wx = wave & 1;
    const int quad = lane >> 4, l16 = lane & 15;

    // staging: tile = 256 rows x 4 chunks of 16B = 1024 chunks; thread covers
    // rows rowA + u*64 (u=0..3), chunk ch, for both A and B.
    const int rowA = tid >> 2, ch = tid & 3;
    const int slot = (ch ^ (rowA & 3)) << 3;       // (rowA+64u)&3 == rowA&3
    const int wL0 = (rowA +   0) * 32 + slot;
    const int wL1 = (rowA +  64) * 32 + slot;
    const int wL2 = (rowA + 128) * 32 + slot;
    const int wL3 = (rowA + 192) * 32 + slot;

    const f16* gA0 = A + (size_t)(i0 + rowA +   0) * lda + ch * 8;
    const f16* gA1 = A + (size_t)(i0 + rowA +  64) * lda + ch * 8;
    const f16* gA2 = A + (size_t)(i0 + rowA + 128) * lda + ch * 8;
    const f16* gA3 = A + (size_t)(i0 + rowA + 192) * lda + ch * 8;
    const f16* gB0 = B + (size_t)(j0 + rowA +   0) * ldb + ch * 8;
    const f16* gB1 = B + (size_t)(j0 + rowA +  64) * ldb + ch * 8;
    const f16* gB2 = B + (size_t)(j0 + rowA + 128) * ldb + ch * 8;
    const f16* gB3 = B + (size_t)(j0 + rowA + 192) * ldb + ch * 8;

    // frag-read slot: quad ^ (row&3); row&3 == l16&3 for all frag rows
    const int xa = (quad ^ (l16 & 3)) << 3;

    const int nt = K >> 5;   // even for all our shapes (16 or 64)

    // prologue: set0 <- tile 0, set1 <- tile 1
    float4 aS0_0 = *(const float4*)(gA0);      float4 aS0_1 = *(const float4*)(gA1);
    float4 aS0_2 = *(const float4*)(gA2);      float4 aS0_3 = *(const float4*)(gA3);
    float4 bS0_0 = *(const float4*)(gB0);      float4 bS0_1 = *(const float4*)(gB1);
    float4 bS0_2 = *(const float4*)(gB2);      float4 bS0_3 = *(const float4*)(gB3);
    float4 aS1_0 = *(const float4*)(gA0 + 32); float4 aS1_1 = *(const float4*)(gA1 + 32);
    float4 aS1_2 = *(const float4*)(gA2 + 32); float4 aS1_3 = *(const float4*)(gA3 + 32);
    float4 bS1_0 = *(const float4*)(gB0 + 32); float4 bS1_1 = *(const float4*)(gB1 + 32);
    float4 bS1_2 = *(const float4*)(gB2 + 32); float4 bS1_3 = *(const float4*)(gB3 + 32);

    floatx4 acc[8][8] = {};

    for (int t = 0; t < nt; t += 2) {
        // ---- even iter: buffer 0, set 0 ----
        *(float4*)&As[0][wL0] = aS0_0; *(float4*)&As[0][wL1] = aS0_1;
        *(float4*)&As[0][wL2] = aS0_2; *(float4*)&As[0][wL3] = aS0_3;
        *(float4*)&Bs[0][wL0] = bS0_0; *(float4*)&Bs[0][wL1] = bS0_1;
        *(float4*)&Bs[0][wL2] = bS0_2; *(float4*)&Bs[0][wL3] = bS0_3;
        if (t + 2 < nt) {
            const int off = (t + 2) * 32;
            aS0_0 = *(const float4*)(gA0 + off); aS0_1 = *(const float4*)(gA1 + off);
            aS0_2 = *(const float4*)(gA2 + off); aS0_3 = *(const float4*)(gA3 + off);
            bS0_0 = *(const float4*)(gB0 + off); bS0_1 = *(const float4*)(gB1 + off);
            bS0_2 = *(const float4*)(gB2 + off); bS0_3 = *(const float4*)(gB3 + off);
        }
        __syncthreads();
        COMPUTE(0)
        // ---- odd iter: buffer 1, set 1 ----
        *(float4*)&As[1][wL0] = aS1_0; *(float4*)&As[1][wL1] = aS1_1;
        *(float4*)&As[1][wL2] = aS1_2; *(float4*)&As[1][wL3] = aS1_3;
        *(float4*)&Bs[1][wL0] = bS1_0; *(float4*)&Bs[1][wL1] = bS1_1;
        *(float4*)&Bs[1][wL2] = bS1_2; *(float4*)&Bs[1][wL3] = bS1_3;
        if (t + 3 < nt) {
            const int off = (t + 3) * 32;
            aS1_0 = *(const float4*)(gA0 + off); aS1_1 = *(const float4*)(gA1 + off);
            aS1_2 = *(const float4*)(gA2 + off); aS1_3 = *(const float4*)(gA3 + off);
            bS1_0 = *(const float4*)(gB0 + off); bS1_1 = *(const float4*)(gB1 + off);
            bS1_2 = *(const float4*)(gB2 + off); bS1_3 = *(const float4*)(gB3 + off);
        }
        __syncthreads();
        COMPUTE(1)
    }

    // epilogue: C/D layout col = lane&15, row = quad*4 + reg (m89-verified)
    #pragma unroll
    for (int mi = 0; mi < 8; ++mi) {
        #pragma unroll
        for (int ni = 0; ni < 8; ++ni) {
            const int col = j0 + wx * 128 + ni * 16 + l16;
            #pragma unroll
            for (int r = 0; r < 4; ++r) {
                const int row = i0 + wy * 128 + mi * 16 + quad * 4 + r;
                float v = acc[mi][ni][r];
                if (MODE == 1) { v += bias[col]; v = v > 0.f ? v : 0.f; }
                if (MODE == 2) { v += bias[row]; v = v > 0.f ? v : 0.f; }
                if (MODE == 3) {
                    v += bias[row];
                    v = v > 0.f ? v : 0.f;
                    v += resid[(size_t)bz * sR + (size_t)row * ldc + col];
                    ((float*)Cp)[(size_t)bz * sC + (size_t)row * ldc + col] = v;
                } else {
                    ((f16*)Cp)[(size_t)bz * sC + (size_t)row * ldc + col] = (f16)v;
                }
            }
        }
    }
}

// ---------------------------------------------------------------------------
// in-place fp16 softmax over rows of 2048 (fp32 math)
// ---------------------------------------------------------------------------
__global__ __launch_bounds__(256) void softmax_f16_kernel(f16* __restrict__ S)
{
    f16* p = S + (size_t)blockIdx.x * T_DIM;
    const int tid = threadIdx.x;

    half8 hv = *((const half8*)p + tid);
    float v[8];
    float lmax = -1e30f;
    #pragma unroll
    for (int c = 0; c < 8; ++c) { v[c] = (float)hv[c]; lmax = fmaxf(lmax, v[c]); }
    #pragma unroll
    for (int off = 32; off; off >>= 1)
        lmax = fmaxf(lmax, __shfl_down(lmax, off));
    __shared__ float redm[4];
    if ((tid & 63) == 0) redm[tid >> 6] = lmax;
    __syncthreads();
    const float m = fmaxf(fmaxf(redm[0], redm[1]), fmaxf(redm[2], redm[3]));

    float lsum = 0.f;
    #pragma unroll
    for (int c = 0; c < 8; ++c) { v[c] = __expf(v[c] - m); lsum += v[c]; }
    #pragma unroll
    for (int off = 32; off; off >>= 1)
        lsum += __shfl_down(lsum, off);
    __shared__ float reds[4];
    if ((tid & 63) == 0) reds[tid >> 6] = lsum;
    __syncthreads();
    const float inv = 1.f / (reds[0] + reds[1] + reds[2] + reds[3]);

    #pragma unroll
    for (int c = 0; c < 8; ++c) hv[c] = (f16)(v[c] * inv);
    *((half8*)p + tid) = hv;
}

// ---------------------------------------------------------------------------
extern "C" void kernel_launch(void* const* d_in, const int* in_sizes, int n_in,
                              void* d_out, int out_size, void* d_ws, size_t ws_size,
                              hipStream_t stream)
{
    const float* x       = (const float*)d_in[0];
    const float* w_theta = (const float*)d_in[1];
    const float* b_theta = (const float*)d_in[2];
    const float* w_phi   = (const float*)d_in[3];
    const float* b_phi   = (const float*)d_in[4];
    const float* w_g     = (const float*)d_in[5];
    const float* b_g     = (const float*)d_in[6];
    const float* w_w     = (const float*)d_in[7];
    const float* b_w     = (const float*)d_in[8];
    float* out = (float*)d_out;

    const size_t FE = (size_t)B_DIM * C_DIM * T_DIM;   // 8.4M
    const size_t TC = (size_t)T_DIM * C_DIM;
    const size_t TT = (size_t)T_DIM * T_DIM;

    f16* xt      = (f16*)d_ws;
    f16* wtp     = xt + FE;              // merged theta|phi weights [1024][512]
    f16* wg_h    = wtp + 524288;
    f16* ww_h    = wg_h + 262144;
    float* btp   = (float*)(ww_h + 262144);   // merged bias [1024] fp32
    f16* tp      = (f16*)(btp + 1024);   // theta|phi acts [B][T][1024]
    f16* g       = tp + (size_t)B_DIM * T_DIM * 1024;
    f16* scores  = g + FE;               // B*T*T f16 = 67 MB
    f16* feature = tp;                   // tp dead after scores GEMM

    const dim3 blk(256);

    prep_kernel<<<dim3(64, 16, 9), blk, 0, stream>>>(
        x, xt, w_theta, w_phi, w_g, w_w,
        wtp, wtp + 262144, wg_h, ww_h, b_theta, b_phi, btp);

    // merged theta|phi conv: tp[t][0:1024] = relu(xt . wtp + btp)  M=T,N=1024
    gemm_big<1><<<dim3(4, 8, B_DIM), blk, 0, stream>>>(
        xt, TC, C_DIM, wtp, 0, C_DIM, tp, (size_t)T_DIM * 1024, 1024,
        btp, nullptr, 0, C_DIM, 2, 2);
    // g[c][t] = relu(w_g . xt + b_g[c])   M=C, N=T
    gemm_big<2><<<dim3(8, 2, B_DIM), blk, 0, stream>>>(
        wg_h, 0, C_DIM, xt, TC, C_DIM, g, TC, T_DIM,
        b_g, nullptr, 0, C_DIM, 1, 2);
    // scores[i][j] = theta . phi   (theta = tp cols 0:512, phi = cols 512:1024)
    gemm_big<0><<<dim3(8, 8, B_DIM), blk, 0, stream>>>(
        tp, (size_t)T_DIM * 1024, 1024, tp + 512, (size_t)T_DIM * 1024, 1024,
        scores, TT, T_DIM, nullptr, nullptr, 0, C_DIM, 2, 4);
    softmax_f16_kernel<<<dim3(B_DIM * T_DIM), blk, 0, stream>>>(scores);
    // feature[i][c] = attn . g   M=T, N=C, K=T
    gemm_big<0><<<dim3(2, 8, B_DIM), blk, 0, stream>>>(
        scores, TT, T_DIM, g, TC, T_DIM, feature, TC, C_DIM,
        nullptr, nullptr, 0, T_DIM, 2, 1);
    // out[c][t] = relu(w_w . feature + b_w[c]) + x   M=C, N=T
    gemm_big<3><<<dim3(8, 2, B_DIM), blk, 0, stream>>>(
        ww_h, 0, C_DIM, feature, TC, C_DIM, out, TC, T_DIM,
        b_w, x, TC, C_DIM, 1, 2);
}

// Round 11
// 277.159 us; speedup vs baseline: 1.7605x; 1.7203x over previous
//
#include <hip/hip_runtime.h>
#include <math.h>

#define C_DIM 512
#define T_DIM 2048
#define B_DIM 8

typedef _Float16 f16;
typedef __attribute__((ext_vector_type(8))) _Float16 half8;
typedef __attribute__((ext_vector_type(4))) _Float16 half4;
typedef __attribute__((ext_vector_type(4))) float floatx4;

// ---------------------------------------------------------------------------
// prep: z<8 -> transpose x[b=z] [C][T] fp32 -> xt [T][C] fp16 (32x32 tiles);
//       z==8 -> convert 4 weight matrices to fp16 (+ concat theta/phi bias).
// ---------------------------------------------------------------------------
__global__ __launch_bounds__(256) void prep_kernel(
    const float* __restrict__ x, f16* __restrict__ xt,
    const float* __restrict__ w0, const float* __restrict__ w1,
    const float* __restrict__ w2, const float* __restrict__ w3,
    f16* __restrict__ o0, f16* __restrict__ o1,
    f16* __restrict__ o2, f16* __restrict__ o3,
    const float* __restrict__ b0, const float* __restrict__ b1,
    float* __restrict__ btp)
{
    const int tid = threadIdx.x;
    if (blockIdx.z == 8) {
        const int idx = blockIdx.y * 64 + blockIdx.x;    // 0..1023
        const int wsel = idx >> 8, blk = idx & 255;
        const float* src; f16* dst;
        switch (wsel) {
            case 0:  src = w0; dst = o0; break;
            case 1:  src = w1; dst = o1; break;
            case 2:  src = w2; dst = o2; break;
            default: src = w3; dst = o3; break;
        }
        const int e = blk * 1024 + tid * 4;
        const float4 v = *(const float4*)(src + e);
        half4 h; h[0] = (f16)v.x; h[1] = (f16)v.y; h[2] = (f16)v.z; h[3] = (f16)v.w;
        *(half4*)(dst + e) = h;
        if (idx == 0) {
            const int i = tid * 4;
            const float4 bv = (i < 512) ? *(const float4*)(b0 + i)
                                        : *(const float4*)(b1 + i - 512);
            *(float4*)(btp + i) = bv;
        }
        return;
    }
    __shared__ float xs[32][33];
    const int b  = blockIdx.z;
    const int t0 = blockIdx.x * 32, c0 = blockIdx.y * 32;
    const float* xb = x + (size_t)b * C_DIM * T_DIM;
    const int r = tid >> 3, q = tid & 7;

    const float4 v = *(const float4*)(xb + (size_t)(c0 + r) * T_DIM + t0 + q * 4);
    xs[r][q * 4 + 0] = v.x; xs[r][q * 4 + 1] = v.y;
    xs[r][q * 4 + 2] = v.z; xs[r][q * 4 + 3] = v.w;
    __syncthreads();

    f16* xtb = xt + (size_t)b * C_DIM * T_DIM;
    half4 h;
    h[0] = (f16)xs[q * 4 + 0][r]; h[1] = (f16)xs[q * 4 + 1][r];
    h[2] = (f16)xs[q * 4 + 2][r]; h[3] = (f16)xs[q * 4 + 3][r];
    *(half4*)(xtb + (size_t)(t0 + r) * C_DIM + c0 + q * 4) = h;
}

// ---------------------------------------------------------------------------
// RECT-TILE TN MFMA GEMM: C[i][j] = sum_k A[i][k] * B[j][k]
// Block 256(M) x 128(N), 4 waves, wave tile 128x64: acc[8][4] = 128 VGPR --
// half of R10's 256 (which hit the register wall: VGPR capped, 9.5% util).
// vs R6 (64x64 wave): per-FLOP global fetch 0.75x, per-FLOP LDS reads 0.75x,
// barriers per FLOP 0.5x. R6's measured 26% cap was the co-binding of
// global path (~53/60 B/cyc) + LDS path + per-iter latency; this relaxes all
// three. Distance-1 named-register prefetch (iter ~620 cyc > load latency;
// ds_write reads regs at issue, reload after is WAR-safe in-order).
// Register budget ~230 -> 2 waves/SIMD; LDS 48 KB -> 2 blocks/CU.
// XOR slot swizzle; XCD-aware tile remap (R7: FETCH 148->49 MB).
// MODE: 0 = f16 store; 1 = f16 relu(+bias[col]); 2 = f16 relu(+bias[row]);
// 3 = fp32 relu(+bias[row]) + resid.
// ---------------------------------------------------------------------------
#define COMPUTE(P)                                                            \
    {                                                                         \
        half8 af[8], bf[4];                                                   \
        _Pragma("unroll")                                                     \
        for (int mi = 0; mi < 8; ++mi)                                        \
            af[mi] = *(const half8*)&As[P][(wy * 128 + mi * 16 + l16) * 32 + xa]; \
        _Pragma("unroll")                                                     \
        for (int ni = 0; ni < 4; ++ni)                                        \
            bf[ni] = *(const half8*)&Bs[P][(wx * 64 + ni * 16 + l16) * 32 + xa];  \
        _Pragma("unroll")                                                     \
        for (int mi = 0; mi < 8; ++mi)                                        \
            _Pragma("unroll")                                                 \
            for (int ni = 0; ni < 4; ++ni)                                    \
                acc[mi][ni] = __builtin_amdgcn_mfma_f32_16x16x32_f16(         \
                    af[mi], bf[ni], acc[mi][ni], 0, 0, 0);                    \
    }

template<int MODE>
__global__ __launch_bounds__(256, 2) void gemm_rect(
    const f16* __restrict__ A, size_t sA, int lda,
    const f16* __restrict__ B, size_t sB, int ldb,
    void* __restrict__ Cp, size_t sC, int ldc,
    const float* __restrict__ bias,
    const float* __restrict__ resid, size_t sR,
    int K, int RI, int RJ)
{
    __shared__ __align__(16) f16 As[2][256 * 32];   // 2 x 16 KB
    __shared__ __align__(16) f16 Bs[2][128 * 32];   // 2 x  8 KB

    // XCD-aware tile mapping: 8 regions of RI x RJ tiles, one per XCD
    const int gx = gridDim.x;
    const int flat = blockIdx.y * gx + blockIdx.x;
    const int region = flat & 7;
    const int idx = flat >> 3;
    const int NRJ = gx / RJ;
    const int rI = region / NRJ, rJ = region % NRJ;
    const int ii = idx / RJ, jj = idx % RJ;
    const int i0 = (rI * RI + ii) * 256;
    const int j0 = (rJ * RJ + jj) * 128;

    const int bz = blockIdx.z;
    A += (size_t)bz * sA;
    B += (size_t)bz * sB;

    const int tid  = threadIdx.x;
    const int lane = tid & 63;
    const int wave = tid >> 6;
    const int wy = wave >> 1, wx = wave & 1;
    const int quad = lane >> 4, l16 = lane & 15;

    // staging: A tile 256 rows x 4 chunks (rows rowA+64u, u=0..3);
    //          B tile 128 rows x 4 chunks (rows rowA+64u, u=0..1).
    const int rowA = tid >> 2, ch = tid & 3;
    const int slot = (ch ^ (rowA & 3)) << 3;       // (rowA+64u)&3 == rowA&3
    const int wL0 = (rowA +   0) * 32 + slot;
    const int wL1 = (rowA +  64) * 32 + slot;
    const int wL2 = (rowA + 128) * 32 + slot;
    const int wL3 = (rowA + 192) * 32 + slot;

    const f16* gA0 = A + (size_t)(i0 + rowA +   0) * lda + ch * 8;
    const f16* gA1 = A + (size_t)(i0 + rowA +  64) * lda + ch * 8;
    const f16* gA2 = A + (size_t)(i0 + rowA + 128) * lda + ch * 8;
    const f16* gA3 = A + (size_t)(i0 + rowA + 192) * lda + ch * 8;
    const f16* gB0 = B + (size_t)(j0 + rowA +   0) * ldb + ch * 8;
    const f16* gB1 = B + (size_t)(j0 + rowA +  64) * ldb + ch * 8;

    // frag-read slot: quad ^ (row&3); row&3 == l16&3 for all frag rows
    const int xa = (quad ^ (l16 & 3)) << 3;

    const int nt = K >> 5;   // even for all our shapes (16 or 64)

    // prologue: staging set <- tile 0
    float4 aR0 = *(const float4*)(gA0);
    float4 aR1 = *(const float4*)(gA1);
    float4 aR2 = *(const float4*)(gA2);
    float4 aR3 = *(const float4*)(gA3);
    float4 bR0 = *(const float4*)(gB0);
    float4 bR1 = *(const float4*)(gB1);

    floatx4 acc[8][4] = {};

    for (int t = 0; t < nt; t += 2) {
        // ---- even iter: buffer 0 ----
        *(float4*)&As[0][wL0] = aR0; *(float4*)&As[0][wL1] = aR1;
        *(float4*)&As[0][wL2] = aR2; *(float4*)&As[0][wL3] = aR3;
        *(float4*)&Bs[0][wL0] = bR0; *(float4*)&Bs[0][wL1] = bR1;
        {   // prefetch tile t+1 (nt even -> always exists)
            const int off = (t + 1) * 32;
            aR0 = *(const float4*)(gA0 + off); aR1 = *(const float4*)(gA1 + off);
            aR2 = *(const float4*)(gA2 + off); aR3 = *(const float4*)(gA3 + off);
            bR0 = *(const float4*)(gB0 + off); bR1 = *(const float4*)(gB1 + off);
        }
        __syncthreads();
        COMPUTE(0)
        // ---- odd iter: buffer 1 ----
        *(float4*)&As[1][wL0] = aR0; *(float4*)&As[1][wL1] = aR1;
        *(float4*)&As[1][wL2] = aR2; *(float4*)&As[1][wL3] = aR3;
        *(float4*)&Bs[1][wL0] = bR0; *(float4*)&Bs[1][wL1] = bR1;
        if (t + 2 < nt) {
            const int off = (t + 2) * 32;
            aR0 = *(const float4*)(gA0 + off); aR1 = *(const float4*)(gA1 + off);
            aR2 = *(const float4*)(gA2 + off); aR3 = *(const float4*)(gA3 + off);
            bR0 = *(const float4*)(gB0 + off); bR1 = *(const float4*)(gB1 + off);
        }
        __syncthreads();
        COMPUTE(1)
    }

    // epilogue: C/D layout col = lane&15, row = quad*4 + reg (m89-verified)
    #pragma unroll
    for (int mi = 0; mi < 8; ++mi) {
        #pragma unroll
        for (int ni = 0; ni < 4; ++ni) {
            const int col = j0 + wx * 64 + ni * 16 + l16;
            #pragma unroll
            for (int r = 0; r < 4; ++r) {
                const int row = i0 + wy * 128 + mi * 16 + quad * 4 + r;
                float v = acc[mi][ni][r];
                if (MODE == 1) { v += bias[col]; v = v > 0.f ? v : 0.f; }
                if (MODE == 2) { v += bias[row]; v = v > 0.f ? v : 0.f; }
                if (MODE == 3) {
                    v += bias[row];
                    v = v > 0.f ? v : 0.f;
                    v += resid[(size_t)bz * sR + (size_t)row * ldc + col];
                    ((float*)Cp)[(size_t)bz * sC + (size_t)row * ldc + col] = v;
                } else {
                    ((f16*)Cp)[(size_t)bz * sC + (size_t)row * ldc + col] = (f16)v;
                }
            }
        }
    }
}

// ---------------------------------------------------------------------------
// in-place fp16 softmax over rows of 2048 (fp32 math)
// ---------------------------------------------------------------------------
__global__ __launch_bounds__(256) void softmax_f16_kernel(f16* __restrict__ S)
{
    f16* p = S + (size_t)blockIdx.x * T_DIM;
    const int tid = threadIdx.x;

    half8 hv = *((const half8*)p + tid);
    float v[8];
    float lmax = -1e30f;
    #pragma unroll
    for (int c = 0; c < 8; ++c) { v[c] = (float)hv[c]; lmax = fmaxf(lmax, v[c]); }
    #pragma unroll
    for (int off = 32; off; off >>= 1)
        lmax = fmaxf(lmax, __shfl_down(lmax, off));
    __shared__ float redm[4];
    if ((tid & 63) == 0) redm[tid >> 6] = lmax;
    __syncthreads();
    const float m = fmaxf(fmaxf(redm[0], redm[1]), fmaxf(redm[2], redm[3]));

    float lsum = 0.f;
    #pragma unroll
    for (int c = 0; c < 8; ++c) { v[c] = __expf(v[c] - m); lsum += v[c]; }
    #pragma unroll
    for (int off = 32; off; off >>= 1)
        lsum += __shfl_down(lsum, off);
    __shared__ float reds[4];
    if ((tid & 63) == 0) reds[tid >> 6] = lsum;
    __syncthreads();
    const float inv = 1.f / (reds[0] + reds[1] + reds[2] + reds[3]);

    #pragma unroll
    for (int c = 0; c < 8; ++c) hv[c] = (f16)(v[c] * inv);
    *((half8*)p + tid) = hv;
}

// ---------------------------------------------------------------------------
extern "C" void kernel_launch(void* const* d_in, const int* in_sizes, int n_in,
                              void* d_out, int out_size, void* d_ws, size_t ws_size,
                              hipStream_t stream)
{
    const float* x       = (const float*)d_in[0];
    const float* w_theta = (const float*)d_in[1];
    const float* b_theta = (const float*)d_in[2];
    const float* w_phi   = (const float*)d_in[3];
    const float* b_phi   = (const float*)d_in[4];
    const float* w_g     = (const float*)d_in[5];
    const float* b_g     = (const float*)d_in[6];
    const float* w_w     = (const float*)d_in[7];
    const float* b_w     = (const float*)d_in[8];
    float* out = (float*)d_out;

    const size_t FE = (size_t)B_DIM * C_DIM * T_DIM;   // 8.4M
    const size_t TC = (size_t)T_DIM * C_DIM;
    const size_t TT = (size_t)T_DIM * T_DIM;

    f16* xt      = (f16*)d_ws;
    f16* wtp     = xt + FE;              // merged theta|phi weights [1024][512]
    f16* wg_h    = wtp + 524288;
    f16* ww_h    = wg_h + 262144;
    float* btp   = (float*)(ww_h + 262144);   // merged bias [1024] fp32
    f16* tp      = (f16*)(btp + 1024);   // theta|phi acts [B][T][1024]
    f16* g       = tp + (size_t)B_DIM * T_DIM * 1024;
    f16* scores  = g + FE;               // B*T*T f16 = 67 MB
    f16* feature = tp;                   // tp dead after scores GEMM

    const dim3 blk(256);

    prep_kernel<<<dim3(64, 16, 9), blk, 0, stream>>>(
        x, xt, w_theta, w_phi, w_g, w_w,
        wtp, wtp + 262144, wg_h, ww_h, b_theta, b_phi, btp);

    // merged theta|phi conv: tp[t][0:1024] = relu(xt . wtp + btp)  M=T,N=1024
    gemm_rect<1><<<dim3(8, 8, B_DIM), blk, 0, stream>>>(
        xt, TC, C_DIM, wtp, 0, C_DIM, tp, (size_t)T_DIM * 1024, 1024,
        btp, nullptr, 0, C_DIM, 2, 4);
    // g[c][t] = relu(w_g . xt + b_g[c])   M=C=512, N=T=2048
    gemm_rect<2><<<dim3(16, 2, B_DIM), blk, 0, stream>>>(
        wg_h, 0, C_DIM, xt, TC, C_DIM, g, TC, T_DIM,
        b_g, nullptr, 0, C_DIM, 1, 4);
    // scores[i][j] = theta . phi   M=T, N=T
    gemm_rect<0><<<dim3(16, 8, B_DIM), blk, 0, stream>>>(
        tp, (size_t)T_DIM * 1024, 1024, tp + 512, (size_t)T_DIM * 1024, 1024,
        scores, TT, T_DIM, nullptr, nullptr, 0, C_DIM, 4, 4);
    softmax_f16_kernel<<<dim3(B_DIM * T_DIM), blk, 0, stream>>>(scores);
    // feature[i][c] = attn . g   M=T, N=C=512, K=T
    gemm_rect<0><<<dim3(4, 8, B_DIM), blk, 0, stream>>>(
        scores, TT, T_DIM, g, TC, T_DIM, feature, TC, C_DIM,
        nullptr, nullptr, 0, T_DIM, 2, 2);
    // out[c][t] = relu(w_w . feature + b_w[c]) + x   M=C=512, N=T
    gemm_rect<3><<<dim3(16, 2, B_DIM), blk, 0, stream>>>(
        ww_h, 0, C_DIM, feature, TC, C_DIM, out, TC, T_DIM,
        b_w, x, TC, C_DIM, 1, 4);
}